// Round 1
// baseline (411.922 us; speedup 1.0000x reference)
//
#include <hip/hip_runtime.h>

// DIN attention layer: B=2048, L=200, E=128, H=64.
// One workgroup (256 thr) per batch row. keys_b staged once into LDS (bf16,
// XOR-block-swizzled), scored via factored-layer-1 MFMA GEMM, masked softmax,
// then attn@keys from the same LDS copy. HBM reads keys exactly once.

#define NB 2048
#define LE 128   // E
#define LH 64    // H
#define LL 200   // L
#define NMT 13   // M-tiles of 16 rows (208 >= 200)

typedef short bf16x8 __attribute__((ext_vector_type(8)));
typedef float f32x4 __attribute__((ext_vector_type(4)));

__device__ __forceinline__ short f2bf(float f) {  // RNE float->bf16
  unsigned u = __float_as_uint(f);
  u += 0x7fffu + ((u >> 16) & 1u);
  return (short)(u >> 16);
}
__device__ __forceinline__ float bf2f(short h) {
  return __uint_as_float(((unsigned)(unsigned short)h) << 16);
}

struct __align__(16) SM {
  short keys[208 * 128];  // 53248 B. 16B blocks swizzled: block' = block ^ (l&15)
  short h1[4][16 * 72];   // 9216 B. per-wave h1 tile; also WkT scratch + wsum scratch
  float scores[208];      // scores -> exp -> attn (in place)
  float q[128];
  float bias1[64];
  float b2s[64];
  float w3s[64];
  float red[16];
};

__global__ void __launch_bounds__(256, 2)
din_attn(const float* __restrict__ query, const float* __restrict__ keysg,
         const int* __restrict__ mask, const float* __restrict__ W1,
         const float* __restrict__ b1, const float* __restrict__ W2,
         const float* __restrict__ b2, const float* __restrict__ W3,
         const float* __restrict__ no_hist, float* __restrict__ out)
{
  __shared__ SM sm;
  const int b    = blockIdx.x;
  const int t    = threadIdx.x;
  const int lane = t & 63;
  const int wv   = t >> 6;
  const int col  = lane & 15;   // MFMA n/m index
  const int quad = lane >> 4;   // MFMA k-group

  // ---- tiny prologue loads
  int my_mask = 0;
  if (t < LL) my_mask = mask[b * LL + t];
  if (t < LE) sm.q[t] = query[b * LE + t];
  if (t < LH) { sm.b2s[t] = b2[t]; sm.w3s[t] = W3[t]; }
  __syncthreads();

  // ---- stage keys -> regs (26 loads in flight; HBM BW critical path)
  const float4* kg = (const float4*)(keysg + (size_t)b * LL * LE);
  const int lrow = t >> 4, g = t & 15;  // row-within-pass, 8-float block index
  float4 r0[13], r1[13];
  #pragma unroll
  for (int p = 0; p < 13; ++p) {
    int l = p * 16 + lrow;
    int le = (l < LL) ? l : 0;
    r0[p] = kg[le * 32 + g * 2];
    r1[p] = kg[le * 32 + g * 2 + 1];
  }

  // ---- bias1[h] = b1[h] + sum_e q_e*(W1a[e][h] + W1d[e][h])   (wave 0, L2 hits)
  if (t < LH) {
    float acc = 0.f;
    #pragma unroll 8
    for (int e = 0; e < LE; ++e) {
      float w = W1[e * LH + t] + W1[(384 + e) * LH + t];
      acc = fmaf(sm.q[e], w, acc);
    }
    sm.bias1[t] = acc + b1[t];
  }

  // ---- keys: cvt + swizzled LDS store
  #pragma unroll
  for (int p = 0; p < 13; ++p) {
    int l = p * 16 + lrow;
    if (l < LL) {
      bf16x8 v;
      v[0] = f2bf(r0[p].x); v[1] = f2bf(r0[p].y); v[2] = f2bf(r0[p].z); v[3] = f2bf(r0[p].w);
      v[4] = f2bf(r1[p].x); v[5] = f2bf(r1[p].y); v[6] = f2bf(r1[p].z); v[7] = f2bf(r1[p].w);
      int gs = g ^ (l & 15);
      *(bf16x8*)&sm.keys[l * 128 + gs * 8] = v;
    }
  }

  // ---- layer-1 B-frags: Wk[e][h] = W1b - W1d + q_e*W1c, built via LDS scratch
  // in two 64-column halves (coalesced W1 reads), frag layout B[k][n], n=lane&15.
  bf16x8 fB1[4][4];
  short* scratch = &sm.h1[0][0];  // 64 rows x 72 (stride 72 shorts = 144 B)
  #pragma unroll 1
  for (int half = 0; half < 2; ++half) {
    __syncthreads();  // scratch free (iter2: all frag reads of half1 done)
    #pragma unroll
    for (int i = 0; i < 16; ++i) {
      int idx = t + i * 256;
      int e = idx >> 6, h = idx & 63;
      int eg = e + half * 64;
      float w = W1[(128 + eg) * LH + h] - W1[(384 + eg) * LH + h]
              + sm.q[eg] * W1[(256 + eg) * LH + h];
      scratch[h * 72 + e] = f2bf(w);
    }
    __syncthreads();
    #pragma unroll
    for (int n = 0; n < 4; ++n)
      #pragma unroll
      for (int k2 = 0; k2 < 2; ++k2)
        fB1[n][half * 2 + k2] =
            *(const bf16x8*)&scratch[(n * 16 + col) * 72 + k2 * 32 + quad * 8];
  }

  // ---- layer-2 B-frags: W2[k][n] direct gather (small, L2-resident)
  bf16x8 fB2[4][2];
  #pragma unroll
  for (int n = 0; n < 4; ++n)
    #pragma unroll
    for (int k2 = 0; k2 < 2; ++k2) {
      bf16x8 v;
      #pragma unroll
      for (int j = 0; j < 8; ++j) {
        int k = k2 * 32 + quad * 8 + j;
        v[j] = f2bf(W2[k * LH + n * 16 + col]);
      }
      fB2[n][k2] = v;
    }
  __syncthreads();  // scratch -> h1 use; keys fully staged

  // ---- main loop: each wave does M-tiles wv, wv+4, wv+8, wv+12 (uniform 4 iters)
  short* h1w = &sm.h1[wv][0];
  #pragma unroll 1
  for (int it = 0; it < 4; ++it) {
    int mt = wv + it * 4;
    bool live = (mt < NMT);
    if (live) {
      // A-frags: keys[m=mt*16+col][k], k = kt*32+quad*8+j (swizzled block read)
      bf16x8 a[4];
      int row = mt * 16 + col;
      #pragma unroll
      for (int kt = 0; kt < 4; ++kt)
        a[kt] = *(const bf16x8*)&sm.keys[row * 128 + (((kt * 4 + quad) ^ col) * 8)];
      #pragma unroll
      for (int n = 0; n < 4; ++n) {
        f32x4 acc = {0.f, 0.f, 0.f, 0.f};
        #pragma unroll
        for (int kt = 0; kt < 4; ++kt)
          acc = __builtin_amdgcn_mfma_f32_16x16x32_bf16(a[kt], fB1[n][kt], acc, 0, 0, 0);
        float bias = sm.bias1[n * 16 + col];
        #pragma unroll
        for (int i = 0; i < 4; ++i) {  // C layout: row=quad*4+i, col=lane&15
          float v = fmaxf(acc[i] + bias, 0.f);
          h1w[(quad * 4 + i) * 72 + n * 16 + col] = f2bf(v);
        }
      }
    }
    __syncthreads();  // h1 tile visible (also keeps block uniform)
    if (live) {
      bf16x8 a2[2];
      #pragma unroll
      for (int k2 = 0; k2 < 2; ++k2)
        a2[k2] = *(const bf16x8*)&h1w[col * 72 + k2 * 32 + quad * 8];
      float p[4] = {0.f, 0.f, 0.f, 0.f};
      #pragma unroll
      for (int n = 0; n < 4; ++n) {
        f32x4 c2 = {0.f, 0.f, 0.f, 0.f};
        c2 = __builtin_amdgcn_mfma_f32_16x16x32_bf16(a2[0], fB2[n][0], c2, 0, 0, 0);
        c2 = __builtin_amdgcn_mfma_f32_16x16x32_bf16(a2[1], fB2[n][1], c2, 0, 0, 0);
        float bb = sm.b2s[n * 16 + col];
        float w3 = sm.w3s[n * 16 + col];
        #pragma unroll
        for (int i = 0; i < 4; ++i) {
          float v = fmaxf(c2[i] + bb, 0.f);
          p[i] = fmaf(v, w3, p[i]);  // layer 3 fused (b3 dropped: softmax-invariant)
        }
      }
      #pragma unroll
      for (int i = 0; i < 4; ++i) {
        #pragma unroll
        for (int off = 1; off < 16; off <<= 1)
          p[i] += __shfl_xor(p[i], off);  // reduce over 16 cols (stays in quad)
        if (col == 0) sm.scores[mt * 16 + quad * 4 + i] = p[i];
      }
    }
    __syncthreads();
  }

  // ---- masked softmax over L (exactly matches ref: NEG rows -> exp==0 in fp32)
  float sc = (t < LL) ? sm.scores[t] : -3.0e38f;
  float vmax = (my_mask != 0) ? sc : -3.0e38f;
  #pragma unroll
  for (int off = 1; off < 64; off <<= 1) vmax = fmaxf(vmax, __shfl_xor(vmax, off));
  if (lane == 0) sm.red[wv] = vmax;
  __syncthreads();
  float M = fmaxf(fmaxf(sm.red[0], sm.red[1]), fmaxf(sm.red[2], sm.red[3]));
  float ex = (t < LL && my_mask != 0) ? __expf(sc - M) : 0.f;
  float vsum = ex;
  #pragma unroll
  for (int off = 1; off < 64; off <<= 1) vsum += __shfl_xor(vsum, off);
  if (lane == 0) sm.red[4 + wv] = vsum;
  __syncthreads();
  float Z = sm.red[4] + sm.red[5] + sm.red[6] + sm.red[7];
  bool allpad = !(Z > 0.f);
  float rz = allpad ? 0.f : (1.f / Z);
  if (t < 208) sm.scores[t] = (t < LL) ? ex * rz : 0.f;
  __syncthreads();

  // ---- weighted sum: out[e] = sum_l attn_l * keys[l][e] (bf16 LDS, fp32 acc)
  {
    const int part = t >> 5;         // 8 L-partitions of 25
    const int ei = (t & 31) * 4;     // 4 consecutive e per thread
    float a0 = 0.f, a1 = 0.f, a2s = 0.f, a3 = 0.f;
    int l0 = part * 25;
    #pragma unroll 5
    for (int li = 0; li < 25; ++li) {
      int l = l0 + li;
      float aw = sm.scores[l];
      int blk = (ei >> 3) ^ (l & 15);
      const short* kp = &sm.keys[l * 128 + blk * 8 + (ei & 7)];
      int2 kv = *(const int2*)kp;
      unsigned kx = (unsigned)kv.x, ky = (unsigned)kv.y;
      a0  = fmaf(aw, __uint_as_float(kx << 16), a0);
      a1  = fmaf(aw, __uint_as_float(kx & 0xffff0000u), a1);
      a2s = fmaf(aw, __uint_as_float(ky << 16), a2s);
      a3  = fmaf(aw, __uint_as_float(ky & 0xffff0000u), a3);
    }
    float* redf = (float*)&sm.h1[0][0];  // 8 x 128 floats (h1 dead now)
    *(float4*)&redf[part * 128 + ei] = make_float4(a0, a1, a2s, a3);
    __syncthreads();
    if (t < LE) {
      float s = 0.f;
      #pragma unroll
      for (int pp = 0; pp < 8; ++pp) s += redf[pp * 128 + t];
      if (allpad) s = no_hist[t];
      out[b * LE + t] = s;
    }
  }
}

extern "C" void kernel_launch(void* const* d_in, const int* in_sizes, int n_in,
                              void* d_out, int out_size, void* d_ws, size_t ws_size,
                              hipStream_t stream) {
  (void)in_sizes; (void)n_in; (void)d_ws; (void)ws_size; (void)out_size;
  const float* query   = (const float*)d_in[0];
  const float* keysg   = (const float*)d_in[1];
  const int*   mask    = (const int*)d_in[2];
  const float* W1      = (const float*)d_in[3];
  const float* b1      = (const float*)d_in[4];
  const float* W2      = (const float*)d_in[5];
  const float* b2      = (const float*)d_in[6];
  const float* W3      = (const float*)d_in[7];
  // d_in[8] = b3: unused (softmax shift-invariant)
  const float* no_hist = (const float*)d_in[9];
  din_attn<<<NB, 256, 0, stream>>>(query, keysg, mask, W1, b1, W2, b2, W3,
                                   no_hist, (float*)d_out);
}

// Round 2
// 327.351 us; speedup vs baseline: 1.2584x; 1.2584x over previous
//
#include <hip/hip_runtime.h>

// DIN attention layer: B=2048, L=200, E=128, H=64.  R2: latency-bound fix.
// One WG (256 thr) per batch row. A-frags load HBM->reg directly (MFMA A
// layout), barrier-free main loop (per-wave tiles, wave-local h1 transpose),
// b-independent weight algebra precomputed in K0 into d_ws.

#define NB 2048
#define LE 128   // E
#define LH 64    // H
#define LL 200   // L
#define NMT 13   // M-tiles of 16 rows (208 >= 200)

typedef short bf16x8 __attribute__((ext_vector_type(8)));
typedef float f32x4 __attribute__((ext_vector_type(4)));

__device__ __forceinline__ short f2bf(float f) {  // RNE float->bf16
  unsigned u = __float_as_uint(f);
  u += 0x7fffu + ((u >> 16) & 1u);
  return (short)(u >> 16);
}

struct __align__(16) SM {
  short keys[208 * 128];  // 53248 B; prologue overlays Wk scratch (64x136) here
  short h1[4][16 * 72];   // 9216 B; overlays: bias partials (prologue), redf (wsum)
  float scores[208];
  float q[128];
  float bias1[64];
  float b2s[64];
  float w3s[64];
  float red[16];
};  // total 64128 B -> 2 WG/CU

// ---- K0: b-independent weight prep into workspace ------------------------
// BD[h][e] = W1b - W1d ; Cq[h][e] = W1c ; AD[e][h] = W1a + W1d ; W2T[n][k]
__global__ void k0_prep(const float* __restrict__ W1, const float* __restrict__ W2,
                        float* __restrict__ BD, float* __restrict__ Cq,
                        float* __restrict__ AD, short* __restrict__ W2T) {
  int idx = blockIdx.x * 256 + threadIdx.x;  // 32 blocks * 256 = 8192
  if (idx < 8192) {
    int h = idx >> 7, e = idx & 127;
    BD[idx] = W1[(128 + e) * LH + h] - W1[(384 + e) * LH + h];
    Cq[idx] = W1[(256 + e) * LH + h];
    int e2 = idx >> 6, h2 = idx & 63;
    AD[idx] = W1[e2 * LH + h2] + W1[(384 + e2) * LH + h2];
    if (idx < 4096) {
      int c = idx >> 6, k = idx & 63;
      W2T[idx] = f2bf(W2[k * LH + c]);
    }
  }
}

__global__ void __launch_bounds__(256, 2)
din_attn(const float* __restrict__ query, const float* __restrict__ keysg,
         const int* __restrict__ mask, const float* __restrict__ b1,
         const float* __restrict__ b2, const float* __restrict__ W3,
         const float* __restrict__ no_hist,
         const float* __restrict__ BD, const float* __restrict__ Cq,
         const float* __restrict__ AD, const short* __restrict__ W2T,
         float* __restrict__ out)
{
  __shared__ SM sm;
  const int b    = blockIdx.x;
  const int t    = threadIdx.x;
  const int lane = t & 63;
  const int wv   = t >> 6;
  const int col  = lane & 15;   // MFMA m/n index
  const int quad = lane >> 4;   // MFMA k-group

  // ---- prologue: tiny loads
  int my_mask = 0;
  if (t < LL) my_mask = mask[b * LL + t];
  if (t < LE) sm.q[t] = query[b * LE + t];
  if (t < LH) { sm.b2s[t] = b2[t]; sm.w3s[t] = W3[t]; }
  __syncthreads();  // q visible

  // layer-2 B-frags straight from W2T (global, frag-contiguous)
  bf16x8 fB2[4][2];
  #pragma unroll
  for (int n = 0; n < 4; ++n)
    #pragma unroll
    for (int k2 = 0; k2 < 2; ++k2)
      fB2[n][k2] = *(const bf16x8*)&W2T[(n * 16 + col) * 64 + k2 * 32 + quad * 8];

  // Wk[h][e] = BD + q_e*Cq -> bf16 scratch (overlaid on keys region)
  short* scratch = &sm.keys[0];  // 64 rows x 136 shorts
  #pragma unroll
  for (int i = 0; i < 4; ++i) {
    int idx = (t + 256 * i) * 8;
    int h = idx >> 7, e0 = idx & 127;
    float4 bd0 = *(const float4*)&BD[idx];
    float4 bd1 = *(const float4*)&BD[idx + 4];
    float4 c0  = *(const float4*)&Cq[idx];
    float4 c1  = *(const float4*)&Cq[idx + 4];
    bf16x8 w;
    w[0] = f2bf(bd0.x + sm.q[e0 + 0] * c0.x);
    w[1] = f2bf(bd0.y + sm.q[e0 + 1] * c0.y);
    w[2] = f2bf(bd0.z + sm.q[e0 + 2] * c0.z);
    w[3] = f2bf(bd0.w + sm.q[e0 + 3] * c0.w);
    w[4] = f2bf(bd1.x + sm.q[e0 + 4] * c1.x);
    w[5] = f2bf(bd1.y + sm.q[e0 + 5] * c1.y);
    w[6] = f2bf(bd1.z + sm.q[e0 + 6] * c1.z);
    w[7] = f2bf(bd1.w + sm.q[e0 + 7] * c1.w);
    *(bf16x8*)&scratch[h * 136 + e0] = w;
  }
  // bias1 partials: wave wv sums e-quarter wv
  {
    int h = lane;
    float acc = 0.f;
    #pragma unroll 8
    for (int e = wv * 32; e < wv * 32 + 32; ++e)
      acc = fmaf(sm.q[e], AD[e * LH + h], acc);
    float* biasp = (float*)&sm.h1[0][0];  // 4 x 64 floats
    biasp[wv * 64 + h] = acc;
  }
  __syncthreads();  // barrier A: scratch + partials visible

  bf16x8 fB1[4][4];
  #pragma unroll
  for (int n = 0; n < 4; ++n)
    #pragma unroll
    for (int kt = 0; kt < 4; ++kt)
      fB1[n][kt] = *(const bf16x8*)&scratch[(n * 16 + col) * 136 + kt * 32 + quad * 8];

  if (t < LH) {
    const float* biasp = (const float*)&sm.h1[0][0];
    sm.bias1[t] = b1[t] + biasp[t] + biasp[64 + t] + biasp[128 + t] + biasp[192 + t];
  }
  __syncthreads();  // barrier B: frags read (keys area free), bias1 ready

  // ---- barrier-free main loop: wave wv owns tiles {wv, wv+4, wv+8} (+12 for wv==0)
  const float* kb = keysg + (size_t)b * LL * LE;
  short* h1w = &sm.h1[wv][0];

  auto do_tile = [&](int mt) {
    int row = mt * 16 + col;
    int rowg = row < LL ? row : LL - 1;       // clamp only matters for mt==12
    const float* rp = kb + rowg * LE;
    bf16x8 a[4];
    #pragma unroll
    for (int kt = 0; kt < 4; ++kt) {
      float4 v0 = *(const float4*)&rp[kt * 32 + quad * 8];
      float4 v1 = *(const float4*)&rp[kt * 32 + quad * 8 + 4];
      bf16x8 av;
      av[0] = f2bf(v0.x); av[1] = f2bf(v0.y); av[2] = f2bf(v0.z); av[3] = f2bf(v0.w);
      av[4] = f2bf(v1.x); av[5] = f2bf(v1.y); av[6] = f2bf(v1.z); av[7] = f2bf(v1.w);
      a[kt] = av;
      // keys copy for wsum: 16B blocks XOR-swizzled by row&15 (==col here)
      *(bf16x8*)&sm.keys[row * 128 + (((kt * 4 + quad) ^ col) * 8)] = av;
    }
    #pragma unroll
    for (int n = 0; n < 4; ++n) {
      f32x4 acc = {0.f, 0.f, 0.f, 0.f};
      #pragma unroll
      for (int kt = 0; kt < 4; ++kt)
        acc = __builtin_amdgcn_mfma_f32_16x16x32_bf16(a[kt], fB1[n][kt], acc, 0, 0, 0);
      float bias = sm.bias1[n * 16 + col];
      #pragma unroll
      for (int i = 0; i < 4; ++i)  // C layout: row=quad*4+i, col
        h1w[(quad * 4 + i) * 72 + n * 16 + col] = f2bf(fmaxf(acc[i] + bias, 0.f));
    }
    bf16x8 a2[2];  // wave-local LDS round-trip (no __syncthreads needed)
    #pragma unroll
    for (int k2 = 0; k2 < 2; ++k2)
      a2[k2] = *(const bf16x8*)&h1w[col * 72 + k2 * 32 + quad * 8];
    float p[4] = {0.f, 0.f, 0.f, 0.f};
    #pragma unroll
    for (int n = 0; n < 4; ++n) {
      f32x4 c2 = {0.f, 0.f, 0.f, 0.f};
      c2 = __builtin_amdgcn_mfma_f32_16x16x32_bf16(a2[0], fB2[n][0], c2, 0, 0, 0);
      c2 = __builtin_amdgcn_mfma_f32_16x16x32_bf16(a2[1], fB2[n][1], c2, 0, 0, 0);
      float bb = sm.b2s[n * 16 + col];
      float w3 = sm.w3s[n * 16 + col];
      #pragma unroll
      for (int i = 0; i < 4; ++i)
        p[i] = fmaf(fmaxf(c2[i] + bb, 0.f), w3, p[i]);  // layer 3 fused; b3 dropped
    }
    #pragma unroll
    for (int i = 0; i < 4; ++i) {
      #pragma unroll
      for (int off = 1; off < 16; off <<= 1)
        p[i] += __shfl_xor(p[i], off);  // reduce over 16 cols
      if (col == 0) sm.scores[mt * 16 + quad * 4 + i] = p[i];
    }
  };

  do_tile(wv);
  do_tile(wv + 4);
  do_tile(wv + 8);
  if (wv == 0) do_tile(12);
  __syncthreads();  // scores + keys LDS complete

  // ---- masked softmax over L (fp32; matches ref incl. all-pad handling)
  float sc = (t < LL) ? sm.scores[t] : -3.0e38f;
  float vmax = (my_mask != 0) ? sc : -3.0e38f;
  #pragma unroll
  for (int off = 1; off < 64; off <<= 1) vmax = fmaxf(vmax, __shfl_xor(vmax, off));
  if (lane == 0) sm.red[wv] = vmax;
  __syncthreads();
  float M = fmaxf(fmaxf(sm.red[0], sm.red[1]), fmaxf(sm.red[2], sm.red[3]));
  float ex = (t < LL && my_mask != 0) ? __expf(sc - M) : 0.f;
  float vsum = ex;
  #pragma unroll
  for (int off = 1; off < 64; off <<= 1) vsum += __shfl_xor(vsum, off);
  if (lane == 0) sm.red[4 + wv] = vsum;
  __syncthreads();
  float Z = sm.red[4] + sm.red[5] + sm.red[6] + sm.red[7];
  bool allpad = !(Z > 0.f);
  float rz = allpad ? 0.f : (1.f / Z);
  if (t < 208) sm.scores[t] = (t < LL) ? ex * rz : 0.f;
  __syncthreads();

  // ---- weighted sum: out[e] = sum_l attn_l * keys[l][e]
  {
    const int part = t >> 5;         // 8 L-partitions of 25
    const int ei = (t & 31) * 4;     // 4 consecutive e per thread
    float a0 = 0.f, a1 = 0.f, a2s = 0.f, a3 = 0.f;
    int l0 = part * 25;
    #pragma unroll 5
    for (int li = 0; li < 25; ++li) {
      int l = l0 + li;
      float aw = sm.scores[l];
      int blk = (ei >> 3) ^ (l & 15);
      const short* kp = &sm.keys[l * 128 + blk * 8 + (ei & 7)];
      int2 kv = *(const int2*)kp;
      unsigned kx = (unsigned)kv.x, ky = (unsigned)kv.y;
      a0  = fmaf(aw, __uint_as_float(kx << 16), a0);
      a1  = fmaf(aw, __uint_as_float(kx & 0xffff0000u), a1);
      a2s = fmaf(aw, __uint_as_float(ky << 16), a2s);
      a3  = fmaf(aw, __uint_as_float(ky & 0xffff0000u), a3);
    }
    float* redf = (float*)&sm.h1[0][0];  // 8 x 128 floats (h1 dead)
    *(float4*)&redf[part * 128 + ei] = make_float4(a0, a1, a2s, a3);
    __syncthreads();
    if (t < LE) {
      float s = 0.f;
      #pragma unroll
      for (int pp = 0; pp < 8; ++pp) s += redf[pp * 128 + t];
      if (allpad) s = no_hist[t];
      out[b * LE + t] = s;
    }
  }
}

extern "C" void kernel_launch(void* const* d_in, const int* in_sizes, int n_in,
                              void* d_out, int out_size, void* d_ws, size_t ws_size,
                              hipStream_t stream) {
  (void)in_sizes; (void)n_in; (void)ws_size; (void)out_size;
  const float* query   = (const float*)d_in[0];
  const float* keysg   = (const float*)d_in[1];
  const int*   mask    = (const int*)d_in[2];
  const float* W1      = (const float*)d_in[3];
  const float* b1      = (const float*)d_in[4];
  const float* W2      = (const float*)d_in[5];
  const float* b2      = (const float*)d_in[6];
  const float* W3      = (const float*)d_in[7];
  // d_in[8] = b3: unused (softmax shift-invariant)
  const float* no_hist = (const float*)d_in[9];

  float* BD  = (float*)d_ws;            // 8192 f32
  float* Cq  = BD + 8192;               // 8192 f32
  float* AD  = Cq + 8192;               // 8192 f32
  short* W2T = (short*)(AD + 8192);     // 4096 bf16   (total 106496 B)

  k0_prep<<<32, 256, 0, stream>>>(W1, W2, BD, Cq, AD, W2T);
  din_attn<<<NB, 256, 0, stream>>>(query, keysg, mask, b1, b2, W3, no_hist,
                                   BD, Cq, AD, W2T, (float*)d_out);
}